// Round 11
// baseline (404.289 us; speedup 1.0000x reference)
//
#include <hip/hip_runtime.h>
#include <hip/hip_bf16.h>
#include <math.h>

// MultiHeadAttention: B=4, S=2048, D=1024, H=16, DK=64, fp32 in/out.
// Round 14:
//  - attention: skewed software pipeline (T15 mechanism). Per iter:
//    vmcnt(0)+barrier (stage-to-drain distance = one full tile) -> stage
//    K(j+2),V(j+1) -> QK^T(j+1) -> softmax(j+1) into packed regs -> PV(j)
//    (reads OLD Pl; per-wave in-order LDS guarantees read-before-write) ->
//    write Pl(j+1). Softmax VALU/trans of j+1 overlaps PV(j) MFMA in-wave.
//    Same FP ops, same tile order -> bit-identical numerics.
//  - GEMMs unchanged from r13 (3-buffer phase-split pipe, best measured).

constexpr int D = 1024;
constexpr int H = 16;
constexpr int DK = 64;
constexpr int PSTR = 72;  // P row stride (u16)

typedef unsigned short u16;
typedef __attribute__((ext_vector_type(8))) short v8s;
typedef __attribute__((ext_vector_type(4))) float v4f;
typedef const __attribute__((address_space(1))) void gvoid;
typedef __attribute__((address_space(3))) void lvoid;
typedef __attribute__((address_space(3))) u16 ls_u16;
typedef __attribute__((address_space(3))) v8s lv8s;

__device__ __forceinline__ u16 rne_bf16(float f) {
  unsigned u = __float_as_uint(f);
  u += 0x7FFFu + ((u >> 16) & 1u);
  return (u16)(u >> 16);
}

__device__ __forceinline__ unsigned pk_bf16(float a, float b) {
  __hip_bfloat162 t = __float22bfloat162_rn(float2{a, b});
  return *reinterpret_cast<unsigned*>(&t);
}

__device__ __forceinline__ void cfence() { asm volatile("" ::: "memory"); }

// ---------------- fp32 -> bf16 hi/lo split ----------------
__device__ __forceinline__ void split_body(const float* __restrict__ in,
                                           u16* __restrict__ hi, u16* __restrict__ lo,
                                           int i)
{
  const float4 v = ((const float4*)in)[i];
  const float f[4] = {v.x, v.y, v.z, v.w};
  ushort4 h, l;
  u16 hh[4], ll[4];
#pragma unroll
  for (int j = 0; j < 4; ++j) {
    const unsigned u = __float_as_uint(f[j]);
    hh[j] = (u16)(u >> 16);
    const float hf = __uint_as_float(u & 0xFFFF0000u);
    ll[j] = rne_bf16(f[j] - hf);
  }
  h.x = hh[0]; h.y = hh[1]; h.z = hh[2]; h.w = hh[3];
  l.x = ll[0]; l.y = ll[1]; l.z = ll[2]; l.w = ll[3];
  ((ushort4*)hi)[i] = h;
  ((ushort4*)lo)[i] = l;
}

// one launch for ALL splits: linear float4 index space =
// [x: n4x) ++ [Wq,Wk,Wv: 3*N4W) ++ [Wo: N4W)
__global__ __launch_bounds__(256) void split_all_kernel(
    const float* __restrict__ x,
    const float* __restrict__ w0, const float* __restrict__ w1,
    const float* __restrict__ w2, const float* __restrict__ w3,
    u16* __restrict__ xs_hi, u16* __restrict__ xs_lo,
    u16* __restrict__ qkv_hi, u16* __restrict__ qkv_lo,
    u16* __restrict__ o_hi, u16* __restrict__ o_lo, int n4x)
{
  constexpr int N4W = (int)(D * (size_t)D / 4);  // 262144 (pow2)
  const int i = blockIdx.x * 256 + threadIdx.x;
  if (i < n4x) {
    split_body(x, xs_hi, xs_lo, i);
    return;
  }
  const int t = i - n4x;
  const int y = t / N4W;        // pow2 -> shift
  const int j = t - y * N4W;
  if (y >= 4) return;
  const float* src = (y == 0) ? w0 : (y == 1) ? w1 : (y == 2) ? w2 : w3;
  const size_t off = (size_t)y * (size_t)(D * (size_t)D);
  u16* hi = (y < 3) ? qkv_hi + off : o_hi;
  u16* lo = (y < 3) ? qkv_lo + off : o_lo;
  split_body(src, hi, lo, j);
}

// ---------------- staging: R rows x 32 cols u16, pre-swizzled source ----------
// LDS chunk c of row r holds global 16B-chunk c ^ ((r>>1)&3); LDS dest linear.
template<int R>
__device__ __forceinline__ void stage_arr(const u16* __restrict__ src, ls_u16* dst,
                                          int tid, int row0, int k0)
{
  const int cg = (tid & 3) ^ ((tid >> 3) & 3);
#pragma unroll
  for (int j = 0; j < R / 128; ++j) {
    const int row = j * 128 + (tid >> 2);
    __builtin_amdgcn_global_load_lds(
        (gvoid*)(src + (size_t)(row0 + row) * D + k0 + cg * 8),
        (lvoid*)(dst + j * 4096 + tid * 8), 16, 0, 0);
  }
}

// ---------------- deep-pipelined split-bf16 GEMM, phase-split (r9/r13 best) --
// BM x BN tile, 512 threads = 8 waves (4m x 2n, 64x64 per wave).
// 3 LDS buffers {Ahi|Alo|Bhi|Blo}, prefetch distance 2, one vmcnt(6)+publish
// barrier per chunk; chunk body = 3 phases {ds_read | stage 2 loads | 16 MFMA}
// separated by raw s_barrier (waves keep vmcnt in flight across them).
// EPI=0: QKV epilogue (bf16 head-split Q/K natural, V transposed).
// EPI=1: fp32 natural + bias.
template<int BM, int BN, int EPI>
__global__ __launch_bounds__(512, 2) void gemm_pipe_kernel(
    const u16* __restrict__ Ahi, const u16* __restrict__ Alo,
    const u16* __restrict__ Whi, const u16* __restrict__ Wlo,
    const float* __restrict__ b0v, const float* __restrict__ b1v, const float* __restrict__ b2v,
    u16* __restrict__ Qb, u16* __restrict__ Kb, u16* __restrict__ Vtb,
    float* __restrict__ C, int S_)
{
  constexpr int TA = BM * 32;            // u16 per A array tile
  constexpr int TB = BN * 32;            // u16 per B array tile
  constexpr int BUFSZ = 2 * TA + 2 * TB; // {Ahi, Alo, Bhi, Blo}
  __shared__ u16 lds[3][BUFSZ];          // 144 KiB for 256x128

  const int tid = threadIdx.x;
  const int lane = tid & 63, w = tid >> 6;
  const int wm = (w >> 1) * 64, wn = (w & 1) * 64;
  const int fr = lane & 15, fq = lane >> 4;
  const int csw = (fq ^ ((fr >> 1) & 3)) * 8;  // swizzled k-chunk (u16 units)

  // XCD-contiguous id, then grouped mapping (GM m-tiles x all n per group):
  // each XCD's sequential run covers a compact 4m x gy region.
  const int gx = gridDim.x;   // m tiles (multiple of GM)
  const int gyd = gridDim.y;  // n tiles
  const int nwg = gx * gyd;   // multiple of 8
  int id = blockIdx.y * gx + blockIdx.x;
  id = (id & 7) * (nwg >> 3) + (id >> 3);
  constexpr int GM = 4;
  const int per_grp = GM * gyd;
  const int grp = id / per_grp;
  const int ing = id - grp * per_grp;
  const int m0 = (grp * GM + (ing & (GM - 1))) * BM;
  const int n0 = (ing / GM) * BN;

  v4f acc[4][4];
#pragma unroll
  for (int mi = 0; mi < 4; ++mi)
#pragma unroll
    for (int ni = 0; ni < 4; ++ni) acc[mi][ni] = (v4f){0.f, 0.f, 0.f, 0.f};

  ls_u16* pb0 = (ls_u16*)&lds[0][0];
  ls_u16* pb1 = (ls_u16*)&lds[1][0];
  ls_u16* pb2 = (ls_u16*)&lds[2][0];

  int aoff[4], boff[4];
#pragma unroll
  for (int i = 0; i < 4; ++i) {
    aoff[i] = (wm + i * 16 + fr) * 32 + csw;           // into Ahi region
    boff[i] = 2 * TA + (wn + i * 16 + fr) * 32 + csw;  // into Bhi region
  }

  // prologue: stage chunks 0 and 1 (12 loads outstanding)
#pragma unroll
  for (int p = 0; p < 2; ++p) {
    ls_u16* pb = (p == 0) ? pb0 : pb1;
    stage_arr<BM>(Ahi, pb, tid, m0, p * 32);
    stage_arr<BM>(Alo, pb + TA, tid, m0, p * 32);
    stage_arr<BN>(Whi, pb + 2 * TA, tid, n0, p * 32);
    stage_arr<BN>(Wlo, pb + 2 * TA + TB, tid, n0, p * 32);
  }

#pragma unroll 2
  for (int k = 0; k < 32; ++k) {
    // chunk k+2 goes into pb2 (its last reader finished before the publish
    // barrier below); clamped tail re-stages chunk 31, keeps vmcnt uniform.
    const int ks = (k + 2 < 32) ? (k + 2) * 32 : 31 * 32;

    // ===== phase 0: publish buf k; read ah,bh; stage Ahi; MFMA hi*hi =====
    asm volatile("s_waitcnt vmcnt(6)" ::: "memory");
    __builtin_amdgcn_s_barrier();
    cfence();

    v8s ah[4], bh[4], tf[4];
#pragma unroll
    for (int i = 0; i < 4; ++i) ah[i] = *(const lv8s*)(pb0 + aoff[i]);
#pragma unroll
    for (int i = 0; i < 4; ++i) bh[i] = *(const lv8s*)(pb0 + boff[i]);
    stage_arr<BM>(Ahi, pb2, tid, m0, ks);  // 2 loads
    __builtin_amdgcn_s_setprio(1);
#pragma unroll
    for (int mi = 0; mi < 4; ++mi)
#pragma unroll
      for (int ni = 0; ni < 4; ++ni)
        acc[mi][ni] = __builtin_amdgcn_mfma_f32_16x16x32_bf16(ah[mi], bh[ni], acc[mi][ni], 0, 0, 0);
    __builtin_amdgcn_s_setprio(0);
    cfence();
    __builtin_amdgcn_s_barrier();
    cfence();

    // ===== phase 1: read al; stage Alo; MFMA lo*hi =====
#pragma unroll
    for (int i = 0; i < 4; ++i) tf[i] = *(const lv8s*)(pb0 + TA + aoff[i]);
    stage_arr<BM>(Alo, pb2 + TA, tid, m0, ks);  // 2 loads
    __builtin_amdgcn_s_setprio(1);
#pragma unroll
    for (int mi = 0; mi < 4; ++mi)
#pragma unroll
      for (int ni = 0; ni < 4; ++ni)
        acc[mi][ni] = __builtin_amdgcn_mfma_f32_16x16x32_bf16(tf[mi], bh[ni], acc[mi][ni], 0, 0, 0);
    __builtin_amdgcn_s_setprio(0);
    cfence();
    __builtin_amdgcn_s_barrier();
    cfence();

    // ===== phase 2: read bl; stage Bhi+Blo; MFMA hi*lo =====
#pragma unroll
    for (int i = 0; i < 4; ++i) tf[i] = *(const lv8s*)(pb0 + boff[i] + TB);
    stage_arr<BN>(Whi, pb2 + 2 * TA, tid, n0, ks);       // 1 load
    stage_arr<BN>(Wlo, pb2 + 2 * TA + TB, tid, n0, ks);  // 1 load
    __builtin_amdgcn_s_setprio(1);
#pragma unroll
    for (int mi = 0; mi < 4; ++mi)
#pragma unroll
      for (int ni = 0; ni < 4; ++ni)
        acc[mi][ni] = __builtin_amdgcn_mfma_f32_16x16x32_bf16(ah[mi], tf[ni], acc[mi][ni], 0, 0, 0);
    __builtin_amdgcn_s_setprio(0);
    cfence();
    // no trailing barrier: next chunk's publish barrier closes phase 2.

    // rotate buffers: read k+1 from pb1, stage k+3 into old pb0
    ls_u16* t = pb0; pb0 = pb1; pb1 = pb2; pb2 = t;
  }

  const int lane4 = fq * 4;
  if constexpr (EPI == 0) {
    const int wsel = n0 >> 10;  // BN=128 block stays within one of Q/K/V
    const float* bias = (wsel == 0) ? b0v : (wsel == 1) ? b1v : b2v;
    u16* Cb = (wsel == 0) ? Qb : (wsel == 1) ? Kb : Vtb;
    const int bb = m0 / S_;     // block spans a single batch (S_ % BM == 0)
    const int s0 = m0 - bb * S_;
#pragma unroll
    for (int mi = 0; mi < 4; ++mi) {
#pragma unroll
      for (int ni = 0; ni < 4; ++ni) {
        const int n = n0 + wn + ni * 16 + fr;
        const int nl = n & (D - 1);
        const float bvv = bias[nl];
        const int h = nl >> 6, dk = nl & 63;
#pragma unroll
        for (int r = 0; r < 4; ++r) {
          const int s = s0 + wm + mi * 16 + lane4 + r;
          const float val = acc[mi][ni][r] + bvv;
          if (wsel < 2)
            Cb[((size_t)(bb * H + h) * S_ + s) * DK + dk] = rne_bf16(val);
          else
            Cb[((size_t)(bb * H + h) * DK + dk) * S_ + s] = rne_bf16(val);
        }
      }
    }
  } else {
#pragma unroll
    for (int mi = 0; mi < 4; ++mi)
#pragma unroll
      for (int ni = 0; ni < 4; ++ni) {
        const int n = n0 + wn + ni * 16 + fr;
        const float bvv = b0v[n];
#pragma unroll
        for (int r = 0; r < 4; ++r) {
          const int m = m0 + wm + mi * 16 + lane4 + r;
          C[(size_t)m * D + n] = acc[mi][ni][r] + bvv;
        }
      }
  }
}

// ---------------- skewed-pipeline MFMA flash attention ----------------------
// grid: 512 blocks = (S/256) x H x B via XCD-contiguous swizzle; block 512
// threads (8 waves); wave w owns Q rows [q0 + w*32, +32).
// Pipeline: per iter jt: {vmcnt(0)+barrier} -> stage K(jt+2),V(jt+1) ->
// QK^T(jt+1) -> softmax(jt+1) into packed regs -> PV(jt) (reads OLD Pl;
// per-wave in-order LDS keeps reads before the later writes) -> write
// Pl(jt+1). Stage-to-drain distance = one full tile; softmax of jt+1
// overlaps PV(jt) MFMA in-wave. Same FP ops/order as r4-r13.
__global__ __launch_bounds__(512, 4) void attn_mfma_kernel(
    const u16* __restrict__ Qb, const u16* __restrict__ Kb, const u16* __restrict__ Vtb,
    u16* __restrict__ Ohi, u16* __restrict__ Olo, int S_)
{
  __shared__ u16 Ks[2][64 * 64];   // Ks[key][dk], XOR-swizzled 16B chunks
  __shared__ u16 Vt[2][64 * 64];   // Vt[dk][key], XOR-swizzled 16B chunks
  __shared__ u16 Pl[8][32 * PSTR]; // per-wave P[q][key]

  const int tid = threadIdx.x;
  const int lane = tid & 63, w = tid >> 6;
  const int fr = lane & 15, fq = lane >> 4;

  // XCD-contiguous swizzle: 64 consecutive swizzled ids (= 8 full (b,h)
  // pairs at gqx=8) land on one XCD -> per-XCD KV footprint ~4MB = L2.
  const int gqx = gridDim.x;
  const int nwg = gqx * gridDim.y * gridDim.z;
  int id = (blockIdx.z * gridDim.y + blockIdx.y) * gqx + blockIdx.x;
  id = (id & 7) * (nwg >> 3) + (id >> 3);
  const int qx = id % gqx;
  const int rest = id / gqx;
  const int h = rest % H;
  const int b = rest / H;

  const int q0 = qx * 256;
  const int wq = w * 32;
  const size_t base = (size_t)(b * H + h) * S_ * DK;

  const int srow = tid >> 3;                 // 0..63
  const int scb = (tid & 7) ^ (srow & 7);    // swizzled 16B chunk

  auto stage_k = [&](int j0, int bufi) {
    __builtin_amdgcn_global_load_lds((gvoid*)(Kb + base + (size_t)(j0 + srow) * DK + scb * 8),
                                     (lvoid*)(&Ks[bufi][0] + tid * 8), 16, 0, 0);
  };
  auto stage_v = [&](int j0, int bufi) {
    __builtin_amdgcn_global_load_lds((gvoid*)(Vtb + base + (size_t)srow * S_ + j0 + scb * 8),
                                     (lvoid*)(&Vt[bufi][0] + tid * 8), 16, 0, 0);
  };

  // prologue: K0 -> buf0, V0 -> buf0, K1 -> buf1
  stage_k(0, 0);
  stage_v(0, 0);
  stage_k(64, 1);

  v8s qa[2][2];
#pragma unroll
  for (int ni = 0; ni < 2; ++ni)
#pragma unroll
    for (int ks = 0; ks < 2; ++ks)
      qa[ni][ks] = *(const v8s*)(Qb + base + (size_t)(q0 + wq + ni * 16 + fr) * DK + ks * 32 + fq * 8);

  v4f o[4][2];
  float lsum[2] = {0.f, 0.f};
#pragma unroll
  for (int mi = 0; mi < 4; ++mi)
#pragma unroll
    for (int ni = 0; ni < 2; ++ni) o[mi][ni] = (v4f){0.f, 0.f, 0.f, 0.f};

  asm volatile("s_waitcnt vmcnt(0)" ::: "memory");
  __builtin_amdgcn_s_barrier();
  cfence();

  uint2 pkv[4][2];  // packed P of the "next" tile, between softmax and Pl write

  // QK^T + softmax of tile `jt` from Ks[bufi] -> pkv (+lsum). FP op order
  // identical to the unskewed version.
  auto qkt_softmax = [&](int bufi) {
    const u16* Kc = &Ks[bufi][0];
    v4f s[4][2];
#pragma unroll
    for (int mi = 0; mi < 4; ++mi)
#pragma unroll
      for (int ni = 0; ni < 2; ++ni) s[mi][ni] = (v4f){0.f, 0.f, 0.f, 0.f};
#pragma unroll
    for (int ks = 0; ks < 2; ++ks) {
      v8s kb[4];
#pragma unroll
      for (int mi = 0; mi < 4; ++mi) {
        const int row = mi * 16 + fr;  // key
        kb[mi] = *(const v8s*)&Kc[row * 64 + (((ks * 4 + fq) ^ (row & 7)) * 8)];
      }
      __builtin_amdgcn_s_setprio(1);
#pragma unroll
      for (int mi = 0; mi < 4; ++mi)
#pragma unroll
        for (int ni = 0; ni < 2; ++ni)
          s[mi][ni] = __builtin_amdgcn_mfma_f32_16x16x32_bf16(kb[mi], qa[ni][ks], s[mi][ni], 0, 0, 0);
      __builtin_amdgcn_s_setprio(0);
    }
#pragma unroll
    for (int mi = 0; mi < 4; ++mi)
#pragma unroll
      for (int ni = 0; ni < 2; ++ni) {
        float p[4];
#pragma unroll
        for (int r = 0; r < 4; ++r) p[r] = __expf(s[mi][ni][r] * 0.125f);
        lsum[ni] += (p[0] + p[1]) + (p[2] + p[3]);
        pkv[mi][ni].x = pk_bf16(p[0], p[1]);
        pkv[mi][ni].y = pk_bf16(p[2], p[3]);
      }
  };

  // prologue compute: tile 0 QK^T+softmax, publish Pl(0)
  qkt_softmax(0);
#pragma unroll
  for (int mi = 0; mi < 4; ++mi)
#pragma unroll
    for (int ni = 0; ni < 2; ++ni)
      *(uint2*)&Pl[w][(ni * 16 + fr) * PSTR + mi * 16 + fq * 4] = pkv[mi][ni];

  const int NT = S_ >> 6;
  for (int jt = 0; jt < NT; ++jt) {
    // drain stages issued one full tile ago (K(jt+1), V(jt)); barrier
    // separates last iter's LDS reads from this iter's stages.
    asm volatile("s_waitcnt vmcnt(0)" ::: "memory");
    cfence();
    __builtin_amdgcn_s_barrier();
    cfence();

    if (jt + 2 < NT) stage_k((jt + 2) * 64, jt & 1);
    if (jt + 1 < NT) stage_v((jt + 1) * 64, (jt + 1) & 1);

    // QK^T + softmax of tile jt+1 (K(jt+1) resident in Ks[(jt+1)&1])
    if (jt + 1 < NT) qkt_softmax((jt + 1) & 1);

    // PV(jt): reads Vt[jt&1] and the OLD Pl (tile jt, written last iter /
    // prologue). Program order puts these ds_reads before the Pl writes
    // below; per-wave LDS ops execute in order.
    {
      const u16* Vc = &Vt[jt & 1][0];
#pragma unroll
      for (int ks = 0; ks < 2; ++ks) {
        v8s vb[4], pa[2];
#pragma unroll
        for (int mi = 0; mi < 4; ++mi) {
          const int row = mi * 16 + fr;  // d
          vb[mi] = *(const v8s*)&Vc[row * 64 + (((ks * 4 + fq) ^ (row & 7)) * 8)];
        }
#pragma unroll
        for (int ni = 0; ni < 2; ++ni)
          pa[ni] = *(const v8s*)&Pl[w][(ni * 16 + fr) * PSTR + ks * 32 + fq * 8];
        __builtin_amdgcn_s_setprio(1);
#pragma unroll
        for (int mi = 0; mi < 4; ++mi)
#pragma unroll
          for (int ni = 0; ni < 2; ++ni)
            o[mi][ni] = __builtin_amdgcn_mfma_f32_16x16x32_bf16(vb[mi], pa[ni], o[mi][ni], 0, 0, 0);
        __builtin_amdgcn_s_setprio(0);
      }
    }

    // publish Pl(jt+1) for next iteration's PV (wave-private region)
    if (jt + 1 < NT) {
#pragma unroll
      for (int mi = 0; mi < 4; ++mi)
#pragma unroll
        for (int ni = 0; ni < 2; ++ni)
          *(uint2*)&Pl[w][(ni * 16 + fr) * PSTR + mi * 16 + fq * 4] = pkv[mi][ni];
    }
  }

  float linv[2];
#pragma unroll
  for (int ni = 0; ni < 2; ++ni) {
    float l = lsum[ni];
    l += __shfl_xor(l, 16);
    l += __shfl_xor(l, 32);
    linv[ni] = 1.f / l;
  }

#pragma unroll
  for (int ni = 0; ni < 2; ++ni) {
    const int q = q0 + wq + ni * 16 + fr;
    const size_t rowbase = (size_t)(b * S_ + q) * D + h * DK;
#pragma unroll
    for (int mi = 0; mi < 4; ++mi) {
      const int d0 = mi * 16 + fq * 4;
      float v[4];
      unsigned u[4];
      float res[4];
#pragma unroll
      for (int r = 0; r < 4; ++r) {
        v[r] = o[mi][ni][r] * linv[ni];
        u[r] = __float_as_uint(v[r]);
        res[r] = v[r] - __uint_as_float(u[r] & 0xFFFF0000u);
      }
      uint2 hi, lo;
      hi.x = (u[1] & 0xFFFF0000u) | (u[0] >> 16);
      hi.y = (u[3] & 0xFFFF0000u) | (u[2] >> 16);
      lo.x = pk_bf16(res[0], res[1]);
      lo.y = pk_bf16(res[2], res[3]);
      *(uint2*)(Ohi + rowbase + d0) = hi;
      *(uint2*)(Olo + rowbase + d0) = lo;
    }
  }
}

extern "C" void kernel_launch(void* const* d_in, const int* in_sizes, int n_in,
                              void* d_out, int out_size, void* d_ws, size_t ws_size,
                              hipStream_t stream) {
  const float* x  = (const float*)d_in[0];
  const float* Wq = (const float*)d_in[1];
  const float* bq = (const float*)d_in[2];
  const float* Wk = (const float*)d_in[3];
  const float* bk = (const float*)d_in[4];
  const float* Wv = (const float*)d_in[5];
  const float* bv = (const float*)d_in[6];
  const float* Wo = (const float*)d_in[7];
  const float* bo = (const float*)d_in[8];

  const int M = in_sizes[0] / D;  // 8192
  const int B = 4;
  const int S_ = M / B;           // 2048
  const size_t MD = (size_t)M * D;
  const size_t DD = (size_t)D * D;

  // ws (u16 units): Qb | Kb | Vtb | xs_hi | xs_lo | Ohi | Olo | wo_hi | wo_lo
  u16* Qb    = (u16*)d_ws;
  u16* Kb    = Qb + MD;
  u16* Vtb   = Kb + MD;
  u16* xs_hi = Vtb + MD;
  u16* xs_lo = xs_hi + MD;
  u16* Ohi   = xs_lo + MD;
  u16* Olo   = Ohi + MD;
  u16* wo_hi = Olo + MD;
  u16* wo_lo = wo_hi + DD;

  // concatenated QKV weight splits live in d_out (dead until final GEMM)
  u16* wqkv_hi = (u16*)d_out;
  u16* wqkv_lo = wqkv_hi + 3 * DD;

  const int n4x = (int)(MD / 4);
  const int n4w = (int)(DD / 4);
  const int nsb = (n4x + 4 * n4w + 255) / 256;
  split_all_kernel<<<nsb, 256, 0, stream>>>(x, Wq, Wk, Wv, Wo,
                                            xs_hi, xs_lo, wqkv_hi, wqkv_lo,
                                            wo_hi, wo_lo, n4x);

  dim3 gq(M / 256, 3 * D / 128);  // (32, 24) -> 768 blocks
  gemm_pipe_kernel<256, 128, 0><<<gq, 512, 0, stream>>>(
      xs_hi, xs_lo, wqkv_hi, wqkv_lo, bq, bk, bv, Qb, Kb, Vtb, nullptr, S_);

  dim3 ga(S_ / 256, H, B);        // (8, 16, 4) -> 512 blocks
  attn_mfma_kernel<<<ga, 512, 0, stream>>>(Qb, Kb, Vtb, Ohi, Olo, S_);

  dim3 go(M / 256, D / 128);      // (32, 8) -> 256 blocks
  gemm_pipe_kernel<256, 128, 1><<<go, 512, 0, stream>>>(
      Ohi, Olo, wo_hi, wo_lo, bo, nullptr, nullptr, nullptr, nullptr, nullptr,
      (float*)d_out, S_);
}

// Round 12
// 385.221 us; speedup vs baseline: 1.0495x; 1.0495x over previous
//
#include <hip/hip_runtime.h>
#include <hip/hip_bf16.h>
#include <math.h>

// MultiHeadAttention: B=4, S=2048, D=1024, H=16, DK=64, fp32 in/out.
// Round 15:
//  - attention: r13 schedule (best measured) + per-mi fused QK^T/softmax to
//    cut VGPR pressure (s[4][2]+kb[4] -> s0,s1+kb0,kb1; ~24-28 fewer live
//    regs under the (512,4) 128-VGPR cap). FP op order identical -> bit-
//    identical numerics. r14's skew (regression, likely spill) reverted.
//  - GEMMs + fused split unchanged from r13 (best measured: 150us QKV).

constexpr int D = 1024;
constexpr int H = 16;
constexpr int DK = 64;
constexpr int PSTR = 72;  // P row stride (u16)

typedef unsigned short u16;
typedef __attribute__((ext_vector_type(8))) short v8s;
typedef __attribute__((ext_vector_type(4))) float v4f;
typedef const __attribute__((address_space(1))) void gvoid;
typedef __attribute__((address_space(3))) void lvoid;
typedef __attribute__((address_space(3))) u16 ls_u16;
typedef __attribute__((address_space(3))) v8s lv8s;

__device__ __forceinline__ u16 rne_bf16(float f) {
  unsigned u = __float_as_uint(f);
  u += 0x7FFFu + ((u >> 16) & 1u);
  return (u16)(u >> 16);
}

__device__ __forceinline__ unsigned pk_bf16(float a, float b) {
  __hip_bfloat162 t = __float22bfloat162_rn(float2{a, b});
  return *reinterpret_cast<unsigned*>(&t);
}

__device__ __forceinline__ void cfence() { asm volatile("" ::: "memory"); }

// ---------------- fp32 -> bf16 hi/lo split ----------------
__device__ __forceinline__ void split_body(const float* __restrict__ in,
                                           u16* __restrict__ hi, u16* __restrict__ lo,
                                           int i)
{
  const float4 v = ((const float4*)in)[i];
  const float f[4] = {v.x, v.y, v.z, v.w};
  ushort4 h, l;
  u16 hh[4], ll[4];
#pragma unroll
  for (int j = 0; j < 4; ++j) {
    const unsigned u = __float_as_uint(f[j]);
    hh[j] = (u16)(u >> 16);
    const float hf = __uint_as_float(u & 0xFFFF0000u);
    ll[j] = rne_bf16(f[j] - hf);
  }
  h.x = hh[0]; h.y = hh[1]; h.z = hh[2]; h.w = hh[3];
  l.x = ll[0]; l.y = ll[1]; l.z = ll[2]; l.w = ll[3];
  ((ushort4*)hi)[i] = h;
  ((ushort4*)lo)[i] = l;
}

// one launch for ALL splits: linear float4 index space =
// [x: n4x) ++ [Wq,Wk,Wv: 3*N4W) ++ [Wo: N4W)
__global__ __launch_bounds__(256) void split_all_kernel(
    const float* __restrict__ x,
    const float* __restrict__ w0, const float* __restrict__ w1,
    const float* __restrict__ w2, const float* __restrict__ w3,
    u16* __restrict__ xs_hi, u16* __restrict__ xs_lo,
    u16* __restrict__ qkv_hi, u16* __restrict__ qkv_lo,
    u16* __restrict__ o_hi, u16* __restrict__ o_lo, int n4x)
{
  constexpr int N4W = (int)(D * (size_t)D / 4);  // 262144 (pow2)
  const int i = blockIdx.x * 256 + threadIdx.x;
  if (i < n4x) {
    split_body(x, xs_hi, xs_lo, i);
    return;
  }
  const int t = i - n4x;
  const int y = t / N4W;        // pow2 -> shift
  const int j = t - y * N4W;
  if (y >= 4) return;
  const float* src = (y == 0) ? w0 : (y == 1) ? w1 : (y == 2) ? w2 : w3;
  const size_t off = (size_t)y * (size_t)(D * (size_t)D);
  u16* hi = (y < 3) ? qkv_hi + off : o_hi;
  u16* lo = (y < 3) ? qkv_lo + off : o_lo;
  split_body(src, hi, lo, j);
}

// ---------------- staging: R rows x 32 cols u16, pre-swizzled source ----------
// LDS chunk c of row r holds global 16B-chunk c ^ ((r>>1)&3); LDS dest linear.
template<int R>
__device__ __forceinline__ void stage_arr(const u16* __restrict__ src, ls_u16* dst,
                                          int tid, int row0, int k0)
{
  const int cg = (tid & 3) ^ ((tid >> 3) & 3);
#pragma unroll
  for (int j = 0; j < R / 128; ++j) {
    const int row = j * 128 + (tid >> 2);
    __builtin_amdgcn_global_load_lds(
        (gvoid*)(src + (size_t)(row0 + row) * D + k0 + cg * 8),
        (lvoid*)(dst + j * 4096 + tid * 8), 16, 0, 0);
  }
}

// ---------------- deep-pipelined split-bf16 GEMM, phase-split (r9/r13 best) --
// BM x BN tile, 512 threads = 8 waves (4m x 2n, 64x64 per wave).
// 3 LDS buffers {Ahi|Alo|Bhi|Blo}, prefetch distance 2, one vmcnt(6)+publish
// barrier per chunk; chunk body = 3 phases {ds_read | stage 2 loads | 16 MFMA}
// separated by raw s_barrier (waves keep vmcnt in flight across them).
// EPI=0: QKV epilogue (bf16 head-split Q/K natural, V transposed).
// EPI=1: fp32 natural + bias.
template<int BM, int BN, int EPI>
__global__ __launch_bounds__(512, 2) void gemm_pipe_kernel(
    const u16* __restrict__ Ahi, const u16* __restrict__ Alo,
    const u16* __restrict__ Whi, const u16* __restrict__ Wlo,
    const float* __restrict__ b0v, const float* __restrict__ b1v, const float* __restrict__ b2v,
    u16* __restrict__ Qb, u16* __restrict__ Kb, u16* __restrict__ Vtb,
    float* __restrict__ C, int S_)
{
  constexpr int TA = BM * 32;            // u16 per A array tile
  constexpr int TB = BN * 32;            // u16 per B array tile
  constexpr int BUFSZ = 2 * TA + 2 * TB; // {Ahi, Alo, Bhi, Blo}
  __shared__ u16 lds[3][BUFSZ];          // 144 KiB for 256x128

  const int tid = threadIdx.x;
  const int lane = tid & 63, w = tid >> 6;
  const int wm = (w >> 1) * 64, wn = (w & 1) * 64;
  const int fr = lane & 15, fq = lane >> 4;
  const int csw = (fq ^ ((fr >> 1) & 3)) * 8;  // swizzled k-chunk (u16 units)

  // XCD-contiguous id, then grouped mapping (GM m-tiles x all n per group):
  // each XCD's sequential run covers a compact 4m x gy region.
  const int gx = gridDim.x;   // m tiles (multiple of GM)
  const int gyd = gridDim.y;  // n tiles
  const int nwg = gx * gyd;   // multiple of 8
  int id = blockIdx.y * gx + blockIdx.x;
  id = (id & 7) * (nwg >> 3) + (id >> 3);
  constexpr int GM = 4;
  const int per_grp = GM * gyd;
  const int grp = id / per_grp;
  const int ing = id - grp * per_grp;
  const int m0 = (grp * GM + (ing & (GM - 1))) * BM;
  const int n0 = (ing / GM) * BN;

  v4f acc[4][4];
#pragma unroll
  for (int mi = 0; mi < 4; ++mi)
#pragma unroll
    for (int ni = 0; ni < 4; ++ni) acc[mi][ni] = (v4f){0.f, 0.f, 0.f, 0.f};

  ls_u16* pb0 = (ls_u16*)&lds[0][0];
  ls_u16* pb1 = (ls_u16*)&lds[1][0];
  ls_u16* pb2 = (ls_u16*)&lds[2][0];

  int aoff[4], boff[4];
#pragma unroll
  for (int i = 0; i < 4; ++i) {
    aoff[i] = (wm + i * 16 + fr) * 32 + csw;           // into Ahi region
    boff[i] = 2 * TA + (wn + i * 16 + fr) * 32 + csw;  // into Bhi region
  }

  // prologue: stage chunks 0 and 1 (12 loads outstanding)
#pragma unroll
  for (int p = 0; p < 2; ++p) {
    ls_u16* pb = (p == 0) ? pb0 : pb1;
    stage_arr<BM>(Ahi, pb, tid, m0, p * 32);
    stage_arr<BM>(Alo, pb + TA, tid, m0, p * 32);
    stage_arr<BN>(Whi, pb + 2 * TA, tid, n0, p * 32);
    stage_arr<BN>(Wlo, pb + 2 * TA + TB, tid, n0, p * 32);
  }

#pragma unroll 2
  for (int k = 0; k < 32; ++k) {
    // chunk k+2 goes into pb2 (its last reader finished before the publish
    // barrier below); clamped tail re-stages chunk 31, keeps vmcnt uniform.
    const int ks = (k + 2 < 32) ? (k + 2) * 32 : 31 * 32;

    // ===== phase 0: publish buf k; read ah,bh; stage Ahi; MFMA hi*hi =====
    asm volatile("s_waitcnt vmcnt(6)" ::: "memory");
    __builtin_amdgcn_s_barrier();
    cfence();

    v8s ah[4], bh[4], tf[4];
#pragma unroll
    for (int i = 0; i < 4; ++i) ah[i] = *(const lv8s*)(pb0 + aoff[i]);
#pragma unroll
    for (int i = 0; i < 4; ++i) bh[i] = *(const lv8s*)(pb0 + boff[i]);
    stage_arr<BM>(Ahi, pb2, tid, m0, ks);  // 2 loads
    __builtin_amdgcn_s_setprio(1);
#pragma unroll
    for (int mi = 0; mi < 4; ++mi)
#pragma unroll
      for (int ni = 0; ni < 4; ++ni)
        acc[mi][ni] = __builtin_amdgcn_mfma_f32_16x16x32_bf16(ah[mi], bh[ni], acc[mi][ni], 0, 0, 0);
    __builtin_amdgcn_s_setprio(0);
    cfence();
    __builtin_amdgcn_s_barrier();
    cfence();

    // ===== phase 1: read al; stage Alo; MFMA lo*hi =====
#pragma unroll
    for (int i = 0; i < 4; ++i) tf[i] = *(const lv8s*)(pb0 + TA + aoff[i]);
    stage_arr<BM>(Alo, pb2 + TA, tid, m0, ks);  // 2 loads
    __builtin_amdgcn_s_setprio(1);
#pragma unroll
    for (int mi = 0; mi < 4; ++mi)
#pragma unroll
      for (int ni = 0; ni < 4; ++ni)
        acc[mi][ni] = __builtin_amdgcn_mfma_f32_16x16x32_bf16(tf[mi], bh[ni], acc[mi][ni], 0, 0, 0);
    __builtin_amdgcn_s_setprio(0);
    cfence();
    __builtin_amdgcn_s_barrier();
    cfence();

    // ===== phase 2: read bl; stage Bhi+Blo; MFMA hi*lo =====
#pragma unroll
    for (int i = 0; i < 4; ++i) tf[i] = *(const lv8s*)(pb0 + boff[i] + TB);
    stage_arr<BN>(Whi, pb2 + 2 * TA, tid, n0, ks);       // 1 load
    stage_arr<BN>(Wlo, pb2 + 2 * TA + TB, tid, n0, ks);  // 1 load
    __builtin_amdgcn_s_setprio(1);
#pragma unroll
    for (int mi = 0; mi < 4; ++mi)
#pragma unroll
      for (int ni = 0; ni < 4; ++ni)
        acc[mi][ni] = __builtin_amdgcn_mfma_f32_16x16x32_bf16(ah[mi], tf[ni], acc[mi][ni], 0, 0, 0);
    __builtin_amdgcn_s_setprio(0);
    cfence();
    // no trailing barrier: next chunk's publish barrier closes phase 2.

    // rotate buffers: read k+1 from pb1, stage k+3 into old pb0
    ls_u16* t = pb0; pb0 = pb1; pb1 = pb2; pb2 = t;
  }

  const int lane4 = fq * 4;
  if constexpr (EPI == 0) {
    const int wsel = n0 >> 10;  // BN=128 block stays within one of Q/K/V
    const float* bias = (wsel == 0) ? b0v : (wsel == 1) ? b1v : b2v;
    u16* Cb = (wsel == 0) ? Qb : (wsel == 1) ? Kb : Vtb;
    const int bb = m0 / S_;     // block spans a single batch (S_ % BM == 0)
    const int s0 = m0 - bb * S_;
#pragma unroll
    for (int mi = 0; mi < 4; ++mi) {
#pragma unroll
      for (int ni = 0; ni < 4; ++ni) {
        const int n = n0 + wn + ni * 16 + fr;
        const int nl = n & (D - 1);
        const float bvv = bias[nl];
        const int h = nl >> 6, dk = nl & 63;
#pragma unroll
        for (int r = 0; r < 4; ++r) {
          const int s = s0 + wm + mi * 16 + lane4 + r;
          const float val = acc[mi][ni][r] + bvv;
          if (wsel < 2)
            Cb[((size_t)(bb * H + h) * S_ + s) * DK + dk] = rne_bf16(val);
          else
            Cb[((size_t)(bb * H + h) * DK + dk) * S_ + s] = rne_bf16(val);
        }
      }
    }
  } else {
#pragma unroll
    for (int mi = 0; mi < 4; ++mi)
#pragma unroll
      for (int ni = 0; ni < 4; ++ni) {
        const int n = n0 + wn + ni * 16 + fr;
        const float bvv = b0v[n];
#pragma unroll
        for (int r = 0; r < 4; ++r) {
          const int m = m0 + wm + mi * 16 + lane4 + r;
          C[(size_t)m * D + n] = acc[mi][ni][r] + bvv;
        }
      }
  }
}

// ---------------- transposed MFMA flash attention, 8-wave 2-phase ----------
// grid: 512 blocks = (S/256) x H x B via XCD-contiguous swizzle; block 512
// threads (8 waves); wave w owns Q rows [q0 + w*32, +32). Double-buffered
// Ks/Vt shared by all waves; stage(j+1) issued before compute(j); ONE
// vmcnt(0)+s_barrier per kv-tile. QK^T/softmax fused per-mi to cut VGPR
// pressure (s0,s1 + kb0,kb1 live instead of s[4][2] + kb[4]); FP op order
// identical to r13 -> bit-identical numerics.
__global__ __launch_bounds__(512, 4) void attn_mfma_kernel(
    const u16* __restrict__ Qb, const u16* __restrict__ Kb, const u16* __restrict__ Vtb,
    u16* __restrict__ Ohi, u16* __restrict__ Olo, int S_)
{
  __shared__ u16 Ks[2][64 * 64];   // Ks[key][dk], XOR-swizzled 16B chunks
  __shared__ u16 Vt[2][64 * 64];   // Vt[dk][key], XOR-swizzled 16B chunks
  __shared__ u16 Pl[8][32 * PSTR]; // per-wave P[q][key]

  const int tid = threadIdx.x;
  const int lane = tid & 63, w = tid >> 6;
  const int fr = lane & 15, fq = lane >> 4;

  // XCD-contiguous swizzle: 64 consecutive swizzled ids (= 8 full (b,h)
  // pairs at gqx=8) land on one XCD -> per-XCD KV footprint ~4MB = L2.
  const int gqx = gridDim.x;
  const int nwg = gqx * gridDim.y * gridDim.z;
  int id = (blockIdx.z * gridDim.y + blockIdx.y) * gqx + blockIdx.x;
  id = (id & 7) * (nwg >> 3) + (id >> 3);
  const int qx = id % gqx;
  const int rest = id / gqx;
  const int h = rest % H;
  const int b = rest / H;

  const int q0 = qx * 256;
  const int wq = w * 32;
  const size_t base = (size_t)(b * H + h) * S_ * DK;

  const int srow = tid >> 3;                 // 0..63
  const int scb = (tid & 7) ^ (srow & 7);    // swizzled 16B chunk

  // stage kv-tile at key offset j0 into buffer bufi (2 loads/thread)
  auto stage_kv = [&](int j0, int bufi) {
    __builtin_amdgcn_global_load_lds((gvoid*)(Kb + base + (size_t)(j0 + srow) * DK + scb * 8),
                                     (lvoid*)(&Ks[bufi][0] + tid * 8), 16, 0, 0);
    __builtin_amdgcn_global_load_lds((gvoid*)(Vtb + base + (size_t)srow * S_ + j0 + scb * 8),
                                     (lvoid*)(&Vt[bufi][0] + tid * 8), 16, 0, 0);
  };

  // prologue: stage tile 0; Q fragment loads ride the same vmcnt(0)
  stage_kv(0, 0);

  v8s qa[2][2];
#pragma unroll
  for (int ni = 0; ni < 2; ++ni)
#pragma unroll
    for (int ks = 0; ks < 2; ++ks)
      qa[ni][ks] = *(const v8s*)(Qb + base + (size_t)(q0 + wq + ni * 16 + fr) * DK + ks * 32 + fq * 8);

  v4f o[4][2];
  float lsum[2] = {0.f, 0.f};
#pragma unroll
  for (int mi = 0; mi < 4; ++mi)
#pragma unroll
    for (int ni = 0; ni < 2; ++ni) o[mi][ni] = (v4f){0.f, 0.f, 0.f, 0.f};

  asm volatile("s_waitcnt vmcnt(0)" ::: "memory");
  __builtin_amdgcn_s_barrier();
  cfence();

  const int NT = S_ >> 6;
  for (int jt = 0; jt < NT; ++jt) {
    const int cur = jt & 1;
    // prefetch next tile into the other buffer: safe — all waves finished
    // reading it (tile jt-1) before the barrier that ended last iteration.
    if (jt + 1 < NT) stage_kv((jt + 1) * 64, cur ^ 1);

    const u16* Kc = &Ks[cur][0];
    const u16* Vc = &Vt[cur][0];

    // ---- fused per-mi: S^T = K.Q^T (4 MFMA) then softmax+Pl write ----
    // Per-acc MFMA order (ks0 then ks1) and lsum add order (mi-major,
    // ni0 then ni1) identical to the unfused r13 version.
#pragma unroll
    for (int mi = 0; mi < 4; ++mi) {
      const int row = mi * 16 + fr;  // key
      const v8s kb0 = *(const v8s*)&Kc[row * 64 + ((fq ^ (row & 7)) * 8)];
      const v8s kb1 = *(const v8s*)&Kc[row * 64 + (((4 + fq) ^ (row & 7)) * 8)];
      v4f s0 = (v4f){0.f, 0.f, 0.f, 0.f};
      v4f s1 = (v4f){0.f, 0.f, 0.f, 0.f};
      __builtin_amdgcn_s_setprio(1);
      s0 = __builtin_amdgcn_mfma_f32_16x16x32_bf16(kb0, qa[0][0], s0, 0, 0, 0);
      s1 = __builtin_amdgcn_mfma_f32_16x16x32_bf16(kb0, qa[1][0], s1, 0, 0, 0);
      s0 = __builtin_amdgcn_mfma_f32_16x16x32_bf16(kb1, qa[0][1], s0, 0, 0, 0);
      s1 = __builtin_amdgcn_mfma_f32_16x16x32_bf16(kb1, qa[1][1], s1, 0, 0, 0);
      __builtin_amdgcn_s_setprio(0);

      float p[4];
#pragma unroll
      for (int r = 0; r < 4; ++r) p[r] = __expf(s0[r] * 0.125f);
      lsum[0] += (p[0] + p[1]) + (p[2] + p[3]);
      uint2 pk0;
      pk0.x = pk_bf16(p[0], p[1]);
      pk0.y = pk_bf16(p[2], p[3]);
      *(uint2*)&Pl[w][fr * PSTR + mi * 16 + fq * 4] = pk0;

#pragma unroll
      for (int r = 0; r < 4; ++r) p[r] = __expf(s1[r] * 0.125f);
      lsum[1] += (p[0] + p[1]) + (p[2] + p[3]);
      uint2 pk1;
      pk1.x = pk_bf16(p[0], p[1]);
      pk1.y = pk_bf16(p[2], p[3]);
      *(uint2*)&Pl[w][(16 + fr) * PSTR + mi * 16 + fq * 4] = pk1;
    }

    // ---- O^T += V^T . P^T : C[d][q] ---- (wave-private Pl, in-wave ordering)
#pragma unroll
    for (int ks = 0; ks < 2; ++ks) {
      v8s vb[4], pa[2];
#pragma unroll
      for (int mi = 0; mi < 4; ++mi) {
        const int row = mi * 16 + fr;  // d
        vb[mi] = *(const v8s*)&Vc[row * 64 + (((ks * 4 + fq) ^ (row & 7)) * 8)];
      }
#pragma unroll
      for (int ni = 0; ni < 2; ++ni)
        pa[ni] = *(const v8s*)&Pl[w][(ni * 16 + fr) * PSTR + ks * 32 + fq * 8];
      __builtin_amdgcn_s_setprio(1);
#pragma unroll
      for (int mi = 0; mi < 4; ++mi)
#pragma unroll
        for (int ni = 0; ni < 2; ++ni)
          o[mi][ni] = __builtin_amdgcn_mfma_f32_16x16x32_bf16(vb[mi], pa[ni], o[mi][ni], 0, 0, 0);
      __builtin_amdgcn_s_setprio(0);
    }

    // publish: stage(jt+1) complete, everyone done reading buf cur.
    asm volatile("s_waitcnt vmcnt(0)" ::: "memory");
    cfence();
    __builtin_amdgcn_s_barrier();
    cfence();
  }

  float linv[2];
#pragma unroll
  for (int ni = 0; ni < 2; ++ni) {
    float l = lsum[ni];
    l += __shfl_xor(l, 16);
    l += __shfl_xor(l, 32);
    linv[ni] = 1.f / l;
  }

#pragma unroll
  for (int ni = 0; ni < 2; ++ni) {
    const int q = q0 + wq + ni * 16 + fr;
    const size_t rowbase = (size_t)(b * S_ + q) * D + h * DK;
#pragma unroll
    for (int mi = 0; mi < 4; ++mi) {
      const int d0 = mi * 16 + fq * 4;
      float v[4];
      unsigned u[4];
      float res[4];
#pragma unroll
      for (int r = 0; r < 4; ++r) {
        v[r] = o[mi][ni][r] * linv[ni];
        u[r] = __float_as_uint(v[r]);
        res[r] = v[r] - __uint_as_float(u[r] & 0xFFFF0000u);
      }
      uint2 hi, lo;
      hi.x = (u[1] & 0xFFFF0000u) | (u[0] >> 16);
      hi.y = (u[3] & 0xFFFF0000u) | (u[2] >> 16);
      lo.x = pk_bf16(res[0], res[1]);
      lo.y = pk_bf16(res[2], res[3]);
      *(uint2*)(Ohi + rowbase + d0) = hi;
      *(uint2*)(Olo + rowbase + d0) = lo;
    }
  }
}

extern "C" void kernel_launch(void* const* d_in, const int* in_sizes, int n_in,
                              void* d_out, int out_size, void* d_ws, size_t ws_size,
                              hipStream_t stream) {
  const float* x  = (const float*)d_in[0];
  const float* Wq = (const float*)d_in[1];
  const float* bq = (const float*)d_in[2];
  const float* Wk = (const float*)d_in[3];
  const float* bk = (const float*)d_in[4];
  const float* Wv = (const float*)d_in[5];
  const float* bv = (const float*)d_in[6];
  const float* Wo = (const float*)d_in[7];
  const float* bo = (const float*)d_in[8];

  const int M = in_sizes[0] / D;  // 8192
  const int B = 4;
  const int S_ = M / B;           // 2048
  const size_t MD = (size_t)M * D;
  const size_t DD = (size_t)D * D;

  // ws (u16 units): Qb | Kb | Vtb | xs_hi | xs_lo | Ohi | Olo | wo_hi | wo_lo
  u16* Qb    = (u16*)d_ws;
  u16* Kb    = Qb + MD;
  u16* Vtb   = Kb + MD;
  u16* xs_hi = Vtb + MD;
  u16* xs_lo = xs_hi + MD;
  u16* Ohi   = xs_lo + MD;
  u16* Olo   = Ohi + MD;
  u16* wo_hi = Olo + MD;
  u16* wo_lo = wo_hi + DD;

  // concatenated QKV weight splits live in d_out (dead until final GEMM)
  u16* wqkv_hi = (u16*)d_out;
  u16* wqkv_lo = wqkv_hi + 3 * DD;

  const int n4x = (int)(MD / 4);
  const int n4w = (int)(DD / 4);
  const int nsb = (n4x + 4 * n4w + 255) / 256;
  split_all_kernel<<<nsb, 256, 0, stream>>>(x, Wq, Wk, Wv, Wo,
                                            xs_hi, xs_lo, wqkv_hi, wqkv_lo,
                                            wo_hi, wo_lo, n4x);

  dim3 gq(M / 256, 3 * D / 128);  // (32, 24) -> 768 blocks
  gemm_pipe_kernel<256, 128, 0><<<gq, 512, 0, stream>>>(
      xs_hi, xs_lo, wqkv_hi, wqkv_lo, bq, bk, bv, Qb, Kb, Vtb, nullptr, S_);

  dim3 ga(S_ / 256, H, B);        // (8, 16, 4) -> 512 blocks
  attn_mfma_kernel<<<ga, 512, 0, stream>>>(Qb, Kb, Vtb, Ohi, Olo, S_);

  dim3 go(M / 256, D / 128);      // (32, 8) -> 256 blocks
  gemm_pipe_kernel<256, 128, 1><<<go, 512, 0, stream>>>(
      Ohi, Olo, wo_hi, wo_lo, bo, nullptr, nullptr, nullptr, nullptr, nullptr,
      (float*)d_out, S_);
}